// Round 16
// baseline (270.494 us; speedup 1.0000x reference)
//
#include <hip/hip_runtime.h>
#include <hip/hip_bf16.h>

// Problem sizes (fixed)
#define Nn 32768   // nodes
#define Ee 131072  // edges
#define Gg 128     // graphs
#define Dd 128

using bf16 = __hip_bfloat16;
typedef __attribute__((ext_vector_type(8))) short bf16x8;
typedef __attribute__((ext_vector_type(4))) float f32x4;

__device__ __forceinline__ float b2f(bf16 v){ return __bfloat162float(v); }
__device__ __forceinline__ bf16  f2b(float v){ return __float2bfloat16(v); }
__device__ __forceinline__ unsigned short bf16bits(float v){
  union { bf16 b; unsigned short u; } cv; cv.b = f2b(v); return cv.u;
}
__device__ __forceinline__ float bfu(unsigned short u){
  return __uint_as_float((unsigned int)u << 16);
}
__device__ __forceinline__ float upk_x(unsigned int v){ return __uint_as_float(v << 16); }
__device__ __forceinline__ float upk_h(unsigned int v){ return __uint_as_float(v & 0xffff0000u); }

// K0: repack weights to bf16 [n][k] (B-operand layout for MFMA)
__global__ __launch_bounds__(128)
void k_wrep(const float* __restrict__ Wbb, const float* __restrict__ Wsb,
            const float* __restrict__ Wcb, const float* __restrict__ Wa,
            const float* __restrict__ Wb2c,
            unsigned short* __restrict__ Wbbp, unsigned short* __restrict__ Wsbp,
            unsigned short* __restrict__ Wcbp, unsigned short* __restrict__ Wap,
            unsigned short* __restrict__ Wb2cp) {
  int mat = blockIdx.x >> 7, n = blockIdx.x & 127, k = threadIdx.x;
  if      (mat == 0) Wbbp [n*128 + k] = bf16bits(Wbb [k*128 + n]);
  else if (mat == 1) Wsbp [n*128 + k] = bf16bits(Wsb [k*128 + n]);
  else if (mat == 2) Wcbp [n*128 + k] = bf16bits(Wcb [k*128 + n]);
  else if (mat == 3) { if (k < 64) Wap[n*64 + k] = bf16bits(Wa[k*128 + n]); }
  else               Wb2cp[n*128 + k] = bf16bits(Wb2c[k*128 + n]);
}

// K1 (MFMA): x = xf@Wa + ba; nmt = softmax_c(x@Wsc); h = relu(x@Wb2c);
// xh = pack(x,h); xonly = bf16 x (for the narrow gather).
__global__ __launch_bounds__(256)
void k_atom(const float* __restrict__ xf, const unsigned short* __restrict__ Wap,
            const float* __restrict__ ba, const float* __restrict__ Wsc,
            const unsigned short* __restrict__ Wb2cp,
            unsigned int* __restrict__ xh, unsigned short* __restrict__ xonly,
            float* __restrict__ nmt) {
  __shared__ unsigned short sxf[64*72];
  __shared__ unsigned short sxb[64*136];
  __shared__ float ss[64*8];
  __shared__ float sWsc[1024];
  int tid = threadIdx.x, n0 = blockIdx.x*64;
  int lane = tid & 63, wv = tid >> 6;
  int m = lane & 15, quad = lane >> 4;
  int rbase = wv*16;
  #pragma unroll
  for (int k = 0; k < 4; ++k) {
    int pos = (tid + k*256)*4;
    int node = pos >> 6, f = pos & 63;
    float4 v = *reinterpret_cast<const float4*>(xf + (size_t)n0*64 + pos);
    ushort4 o;
    o.x = bf16bits(v.x); o.y = bf16bits(v.y); o.z = bf16bits(v.z); o.w = bf16bits(v.w);
    *reinterpret_cast<ushort4*>(&sxf[node*72 + f]) = o;
  }
  for (int j = tid; j < 1024; j += 256) sWsc[j] = Wsc[j];
  __syncthreads();
  f32x4 cx[8];
  #pragma unroll
  for (int nt = 0; nt < 8; ++nt) {
    float bv = ba[nt*16 + m];
    cx[nt] = (f32x4){bv, bv, bv, bv};
  }
  const unsigned short* a1 = &sxf[(rbase + m)*72];
  #pragma unroll
  for (int nt = 0; nt < 8; ++nt) {
    #pragma unroll
    for (int kk = 0; kk < 2; ++kk) {
      int ko = kk*32 + quad*8;
      bf16x8 av = *reinterpret_cast<const bf16x8*>((const short*)a1 + ko);
      bf16x8 bv8 = *reinterpret_cast<const bf16x8*>((const short*)Wap + (nt*16 + m)*64 + ko);
      cx[nt] = __builtin_amdgcn_mfma_f32_16x16x32_bf16(av, bv8, cx[nt], 0, 0, 0);
    }
  }
  #pragma unroll
  for (int nt = 0; nt < 8; ++nt)
    #pragma unroll
    for (int i = 0; i < 4; ++i)
      sxb[(rbase + quad*4 + i)*136 + nt*16 + m] = bf16bits(cx[nt][i]);
  __syncthreads();
  for (int p = tid; p < 512; p += 256) {
    int node = p >> 3, col = p & 7;
    float s = 0.f;
    for (int dd = 0; dd < 128; ++dd)
      s += bfu(sxb[node*136 + dd]) * sWsc[dd*8 + col];
    ss[node*8 + col] = s;
  }
  __syncthreads();
  if (tid < 128) {
    int node = tid >> 1, k = tid & 1;
    float v0 = ss[node*8 + 0 + k], v1 = ss[node*8 + 2 + k];
    float v2 = ss[node*8 + 4 + k], v3 = ss[node*8 + 6 + k];
    float mx = fmaxf(fmaxf(v0, v1), fmaxf(v2, v3));
    float e0 = expf(v0-mx), e1 = expf(v1-mx), e2 = expf(v2-mx), e3 = expf(v3-mx);
    float inv = 1.f / (e0+e1+e2+e3);
    *reinterpret_cast<float4*>(nmt + (size_t)(n0 + node)*8 + k*4) =
        make_float4(e0*inv, e1*inv, e2*inv, e3*inv);
  }
  f32x4 chf[8];
  #pragma unroll
  for (int nt = 0; nt < 8; ++nt) chf[nt] = (f32x4){0.f,0.f,0.f,0.f};
  const unsigned short* a2 = &sxb[(rbase + m)*136];
  #pragma unroll
  for (int nt = 0; nt < 8; ++nt) {
    #pragma unroll
    for (int kk = 0; kk < 4; ++kk) {
      int ko = kk*32 + quad*8;
      bf16x8 av = *reinterpret_cast<const bf16x8*>((const short*)a2 + ko);
      bf16x8 bv8 = *reinterpret_cast<const bf16x8*>((const short*)Wb2cp + (nt*16 + m)*128 + ko);
      chf[nt] = __builtin_amdgcn_mfma_f32_16x16x32_bf16(av, bv8, chf[nt], 0, 0, 0);
    }
  }
  #pragma unroll
  for (int nt = 0; nt < 8; ++nt) {
    #pragma unroll
    for (int i = 0; i < 4; ++i) {
      int row = rbase + quad*4 + i, col = nt*16 + m;
      float hv = fmaxf(chf[nt][i], 0.f);
      unsigned short xb = sxb[row*136 + col];
      xh[(size_t)(n0 + row)*128 + col] =
          ((unsigned int)bf16bits(hv) << 16) | (unsigned int)xb;
      xonly[(size_t)(n0 + row)*128 + col] = xb;
    }
  }
}

// K2 (merged): blocks 0..127  -> per-graph CSR build + sea + den
//              blocks 128..639 -> edge-parallel alpha/w20/beta/gea partials
// osrc entries are packed: (dst_local << 16) | src_local.
__global__ __launch_bounds__(256)
void k_gedge(const int* __restrict__ ei, const float* __restrict__ nmt,
             const float* __restrict__ ea,
             int* __restrict__ osrc, int* __restrict__ rowstart,
             float* __restrict__ sea, float* __restrict__ den,
             float* __restrict__ bnmp, float* __restrict__ geap,
             float* __restrict__ wsump) {
  __shared__ __align__(16) char smem[42576];
  int t = threadIdx.x;
  if (blockIdx.x < Gg) {
    int g = blockIdx.x;
    int* cnt    = (int*)smem;
    int* off    = cnt + 256;
    int* sdl    = off + 256;
    int* ssl    = sdl + 1024;
    int* sorder = ssl + 1024;
    float* den8 = (float*)(sorder + 1024);
    cnt[t] = 0;
    if (t < 8) den8[t] = 0.f;
    __syncthreads();
    #pragma unroll
    for (int j = 0; j < 4; ++j) {
      int e = t + j*256;
      int sl = ei[g*1024 + e] - g*256;
      int dl = ei[Ee + g*1024 + e] - g*256;
      ssl[e] = sl; sdl[e] = dl;
      atomicAdd(&cnt[dl], 1);
    }
    {
      const float4* p = reinterpret_cast<const float4*>(nmt + (size_t)(g*256 + t)*8);
      float4 a = p[0], b = p[1];
      float v[8] = {a.x,a.y,a.z,a.w,b.x,b.y,b.z,b.w};
      #pragma unroll
      for (int i = 0; i < 8; ++i) {
        float s = v[i];
        for (int o = 32; o > 0; o >>= 1) s += __shfl_xor(s, o);
        if ((t & 63) == 0) atomicAdd(&den8[i], s);
      }
    }
    __syncthreads();
    off[t] = cnt[t];
    __syncthreads();
    for (int s = 1; s < 256; s <<= 1) {
      int v = (t >= s) ? off[t - s] : 0;
      __syncthreads();
      off[t] += v;
      __syncthreads();
    }
    int startv = off[t] - cnt[t];
    int mycnt = cnt[t];
    rowstart[g*256 + t] = startv;
    off[t] = startv;
    __syncthreads();
    #pragma unroll
    for (int j = 0; j < 4; ++j) {
      int e = t + j*256;
      int pos = atomicAdd(&off[sdl[e]], 1);
      osrc[g*1024 + pos] = (sdl[e] << 16) | ssl[e];
      sorder[pos] = e;
    }
    __syncthreads();
    float s0x=0,s0y=0,s0z=0,s0w=0, s1x=0,s1y=0,s1z=0,s1w=0;
    float s2x=0,s2y=0,s2z=0,s2w=0, s3x=0,s3y=0,s3z=0,s3w=0;
    for (int jj = startv; jj < startv + mycnt; ++jj) {
      int e = sorder[jj];
      const float4* er = reinterpret_cast<const float4*>(ea + ((size_t)g*1024 + e)*16);
      float4 a0 = er[0], a1 = er[1], a2 = er[2], a3 = er[3];
      s0x+=a0.x; s0y+=a0.y; s0z+=a0.z; s0w+=a0.w;
      s1x+=a1.x; s1y+=a1.y; s1z+=a1.z; s1w+=a1.w;
      s2x+=a2.x; s2y+=a2.y; s2z+=a2.z; s2w+=a2.w;
      s3x+=a3.x; s3y+=a3.y; s3z+=a3.z; s3w+=a3.w;
    }
    float4* so = reinterpret_cast<float4*>(sea + (size_t)(g*256 + t)*16);
    so[0] = make_float4(s0x,s0y,s0z,s0w);
    so[1] = make_float4(s1x,s1y,s1z,s1w);
    so[2] = make_float4(s2x,s2y,s2z,s2w);
    so[3] = make_float4(s3x,s3y,s3z,s3w);
    if (t < 8) den[t*Gg + g] = den8[t];
  } else {
    int bq = blockIdx.x - Gg;
    float* eaT   = (float*)smem;
    float* salT  = eaT + 16*260;
    float* sbeta = salT + 8*260;
    float* red   = sbeta + 8*260;
    float* sga   = red + 20;
    float* snmt  = sga + 256;
    int g = bq >> 2;
    int ebase = g*1024 + (bq & 3)*256;
    for (int j = t; j < 2080; j += 256) sbeta[j] = 0.f;
    if (t < 20) red[t] = 0.f;
    for (int j = t; j < 2048; j += 256) snmt[j] = nmt[(size_t)g*2048 + j];
    __syncthreads();
    int sl = ei[ebase + t] - g*256;
    int dl = ei[Ee + ebase + t] - g*256;
    const float4* ps4 = reinterpret_cast<const float4*>(snmt + sl*8);
    const float4* pt4 = reinterpret_cast<const float4*>(snmt + dl*8);
    float4 sv0 = ps4[0], sv1 = ps4[1], tv0 = pt4[0], tv1 = pt4[1];
    float ps[8] = {sv0.x,sv0.y,sv0.z,sv0.w,sv1.x,sv1.y,sv1.z,sv1.w};
    float pt[8] = {tv0.x,tv0.y,tv0.z,tv0.w,tv1.x,tv1.y,tv1.z,tv1.w};
    float w20[20];
    #pragma unroll
    for (int r = 0; r < 2; ++r) {
      int b = r*4;
      w20[r*10+0] = ps[b+0]*pt[b+1]; w20[r*10+1] = ps[b+0]*pt[b+2];
      w20[r*10+2] = ps[b+0]*pt[b+3]; w20[r*10+3] = ps[b+1]*pt[b+2];
      w20[r*10+4] = ps[b+1]*pt[b+3]; w20[r*10+5] = ps[b+2]*pt[b+3];
      w20[r*10+6] = ps[b+0]*pt[b+0]; w20[r*10+7] = ps[b+1]*pt[b+1];
      w20[r*10+8] = ps[b+2]*pt[b+2]; w20[r*10+9] = ps[b+3]*pt[b+3];
    }
    #pragma unroll
    for (int rc = 0; rc < 8; ++rc) {
      float al = ps[rc]*pt[rc]*pt[rc];
      salT[rc*260 + t] = al;
      atomicAdd(&sbeta[rc*260 + sl], al);
    }
    {
      const float4* ea4 = reinterpret_cast<const float4*>(ea + (size_t)ebase*16);
      #pragma unroll
      for (int k = 0; k < 4; ++k) {
        float4 v = ea4[t*4 + k];
        eaT[(k*4+0)*260 + t] = v.x;
        eaT[(k*4+1)*260 + t] = v.y;
        eaT[(k*4+2)*260 + t] = v.z;
        eaT[(k*4+3)*260 + t] = v.w;
      }
    }
    #pragma unroll
    for (int i = 0; i < 20; ++i) {
      for (int o = 32; o > 0; o >>= 1) w20[i] += __shfl_down(w20[i], o);
    }
    if ((t & 63) == 0) {
      #pragma unroll
      for (int i = 0; i < 20; ++i) atomicAdd(&red[i], w20[i]);
    }
    __syncthreads();
    {
      int rc = t >> 5, j = (t >> 1) & 15, hf = t & 1;
      float a = 0.f;
      int eb = hf*128;
      for (int ee = eb; ee < eb + 128; ++ee)
        a += salT[rc*260 + ee] * eaT[j*260 + ee];
      sga[t] = a;
    }
    __syncthreads();
    if ((t & 1) == 0) {
      int rc = t >> 5, j = (t >> 1) & 15;
      geap[(size_t)bq*128 + rc*16 + j] = sga[t] + sga[t+1];
    }
    if (t < 20) wsump[bq*20 + t] = red[t];
    {
      float4* bo = reinterpret_cast<float4*>(bnmp + (size_t)bq*2048 + t*8);
      bo[0] = make_float4(sbeta[0*260+t], sbeta[1*260+t], sbeta[2*260+t], sbeta[3*260+t]);
      bo[1] = make_float4(sbeta[4*260+t], sbeta[5*260+t], sbeta[6*260+t], sbeta[7*260+t]);
    }
  }
}

// K3: blocks 0..127: bnm[g] = sum of 4 bnmp slots. block 128: wcc + maxv.
__global__ __launch_bounds__(256)
void k_wfin(const float* __restrict__ wsump, const float* __restrict__ bnmp,
            float* __restrict__ wcc, float* __restrict__ maxv,
            float* __restrict__ bnm) {
  int t = threadIdx.x;
  if (blockIdx.x < Gg) {
    int g = blockIdx.x;
    for (int j = t; j < 2048; j += 256) {
      float s = bnmp[(size_t)(g*4+0)*2048 + j] + bnmp[(size_t)(g*4+1)*2048 + j]
              + bnmp[(size_t)(g*4+2)*2048 + j] + bnmp[(size_t)(g*4+3)*2048 + j];
      bnm[(size_t)g*2048 + j] = s;
    }
    return;
  }
  __shared__ float smax[128];
  float mx = 0.f;
  if (t < 128) {
    float w[20];
    #pragma unroll
    for (int i = 0; i < 20; ++i)
      w[i] = wsump[(t*4+0)*20 + i] + wsump[(t*4+1)*20 + i]
           + wsump[(t*4+2)*20 + i] + wsump[(t*4+3)*20 + i];
    #pragma unroll
    for (int r = 0; r < 2; ++r) {
      #pragma unroll
      for (int ij = 0; ij < 16; ++ij) {
        int i = ij >> 2, j = ij & 3;
        float v;
        if (i == j) v = 0.5f * w[r*10 + 6 + i];
        else { int a = i < j ? i : j, b = i < j ? j : i;
               int p = (a == 0) ? (b - 1) : (a == 1) ? (b + 1) : 5;
               v = w[r*10 + p]; }
        wcc[(r*Gg + t)*16 + ij] = v;
        mx = fmaxf(mx, v);
      }
    }
    smax[t] = mx;
  }
  __syncthreads();
  for (int s = 64; s > 0; s >>= 1) {
    if (t < s) smax[t] = fmaxf(smax[t], smax[t + s]);
    __syncthreads();
  }
  if (t == 0) maxv[0] = smax[0];
}

// K4 (pool + agg): node-parallel CSR gather, Gg*32 blocks (8 nodes/block,
// 4 serial nodes/thread); in-edge loop unrolled x4 with independent
// accumulators (4 gather loads in flight). Narrow 2 B/lane gather from xonly.
__global__ __launch_bounds__(256)
void k_poolagg(const unsigned int* __restrict__ xh,
               const unsigned short* __restrict__ xonly,
               const float* __restrict__ nmt, const float* __restrict__ bnm,
               const float* __restrict__ sea, const float* __restrict__ We,
               const int* __restrict__ osrc, const int* __restrict__ rowstart,
               unsigned short* __restrict__ aggbb16,
               float* __restrict__ pnum, float* __restrict__ pabc) {
  __shared__ float combN[1024], combA[1024];
  int t = threadIdx.x, d = t & 127, q = t >> 7;
  int g = blockIdx.x >> 5, e32 = blockIdx.x & 31;
  int nbase = g*256 + e32*8;
  const unsigned short* xg = xonly + (size_t)g*256*128;
  const int* og = osrc + g*1024;
  float w[16];
  #pragma unroll
  for (int j = 0; j < 16; ++j) w[j] = We[j*128 + d];
  float aH[8] = {0,0,0,0,0,0,0,0};
  float aX[8] = {0,0,0,0,0,0,0,0};
  for (int nn = q; nn < 8; nn += 2) {
    int n = nbase + nn, ln = n & 255;
    unsigned int vn = xh[(size_t)n*128 + d];
    float xn = upk_x(vn), hn = upk_h(vn);
    const float4* pp = reinterpret_cast<const float4*>(nmt + (size_t)n*8);
    float4 p0 = pp[0], p1 = pp[1];
    float pc[8] = {p0.x,p0.y,p0.z,p0.w,p1.x,p1.y,p1.z,p1.w};
    const float4* bp = reinterpret_cast<const float4*>(bnm + (size_t)n*8);
    float4 b0 = bp[0], b1 = bp[1];
    float bt[8] = {b0.x,b0.y,b0.z,b0.w,b1.x,b1.y,b1.z,b1.w};
    #pragma unroll
    for (int rc = 0; rc < 8; ++rc) {
      aH[rc] += (pc[rc] + bt[rc])*hn;
      aX[rc] += pc[rc]*xn;
    }
    const float4* sp = reinterpret_cast<const float4*>(sea + (size_t)n*16);
    float4 s0 = sp[0], s1 = sp[1], s2 = sp[2], s3 = sp[3];
    float agg = s0.x*w[0] + s0.y*w[1] + s0.z*w[2] + s0.w*w[3]
              + s1.x*w[4] + s1.y*w[5] + s1.z*w[6] + s1.w*w[7]
              + s2.x*w[8] + s2.y*w[9] + s2.z*w[10]+ s2.w*w[11]
              + s3.x*w[12]+ s3.y*w[13]+ s3.z*w[14]+ s3.w*w[15];
    int start = rowstart[n];
    int end = (ln == 255) ? 1024 : rowstart[n+1];
    float a0 = 0.f, a1 = 0.f, a2 = 0.f, a3 = 0.f;
    int jj = start;
    for (; jj + 3 < end; jj += 4) {
      int q0 = og[jj+0] & 255, q1 = og[jj+1] & 255;
      int q2 = og[jj+2] & 255, q3 = og[jj+3] & 255;
      a0 += bfu(xg[(size_t)q0*128 + d]);
      a1 += bfu(xg[(size_t)q1*128 + d]);
      a2 += bfu(xg[(size_t)q2*128 + d]);
      a3 += bfu(xg[(size_t)q3*128 + d]);
    }
    for (; jj < end; ++jj)
      a0 += bfu(xg[(size_t)(og[jj] & 255)*128 + d]);
    agg += (a0 + a1) + (a2 + a3);
    aggbb16[(size_t)n*128 + d] = bf16bits(agg);
  }
  if (q == 1) {
    #pragma unroll
    for (int rc = 0; rc < 8; ++rc) { combN[rc*128+d] = aH[rc]; combA[rc*128+d] = aX[rc]; }
  }
  __syncthreads();
  if (q == 0) {
    #pragma unroll
    for (int rc = 0; rc < 8; ++rc) {
      pnum[(((size_t)rc*Gg + g)*32 + e32)*128 + d] = aH[rc] + combN[rc*128+d];
      pabc[(((size_t)rc*Gg + g)*32 + e32)*128 + d] = aX[rc] + combA[rc*128+d];
    }
  }
}

// K5: cent_x = (node part + gea@We)/(den+1e-6);
//     h_cent = relu(abc@Wbc + (Wcc_n@cent)@Wcc + cent@Wsc)   (32 partial slots)
__global__ __launch_bounds__(128)
void k_hcent(const float* __restrict__ pnum, const float* __restrict__ den,
             const float* __restrict__ pabc, const float* __restrict__ geap,
             const float* __restrict__ We, const float* __restrict__ wcc,
             const float* __restrict__ maxv,
             const float* __restrict__ Wbc, const float* __restrict__ Wcc_,
             const float* __restrict__ Wsc2, float* __restrict__ hcent) {
  __shared__ float scent[512], sbc[512], sccs[512], swcc[16], sgea[64];
  int tid = threadIdx.x, r = blockIdx.x >> 7, g = blockIdx.x & 127;
  float inv = 1.f / (maxv[0] + 1e-9f);
  if (tid < 16) swcc[tid] = wcc[(r*Gg + g)*16 + tid] * inv;
  if (tid < 64) {
    int c = tid >> 4, j = tid & 15;
    int idx = (r*4 + c)*16 + j;
    sgea[tid] = geap[(size_t)(g*4+0)*128 + idx] + geap[(size_t)(g*4+1)*128 + idx]
              + geap[(size_t)(g*4+2)*128 + idx] + geap[(size_t)(g*4+3)*128 + idx];
  }
  __syncthreads();
  for (int c = 0; c < 4; ++c) {
    int rc = r*4 + c;
    float nv = 0.f, av = 0.f;
    #pragma unroll
    for (int s = 0; s < 32; ++s) {
      nv += pnum[(((size_t)rc*Gg + g)*32 + s)*128 + tid];
      av += pabc[(((size_t)rc*Gg + g)*32 + s)*128 + tid];
    }
    #pragma unroll
    for (int j = 0; j < 16; ++j) nv += sgea[c*16 + j] * We[j*128 + tid];
    float dn = den[rc*Gg + g] + 1e-6f;
    scent[c*128 + tid] = nv / dn;
    sbc[c*128 + tid]   = av;
  }
  __syncthreads();
  for (int i = 0; i < 4; ++i) {
    sccs[i*128 + tid] = swcc[i*4+0]*scent[tid]       + swcc[i*4+1]*scent[128 + tid]
                      + swcc[i*4+2]*scent[256 + tid] + swcc[i*4+3]*scent[384 + tid];
  }
  __syncthreads();
  float acc[4] = {0.f, 0.f, 0.f, 0.f};
  for (int k = 0; k < 128; ++k) {
    float wb = Wbc[k*128 + tid], wc = Wcc_[k*128 + tid], ws2 = Wsc2[k*128 + tid];
    #pragma unroll
    for (int c = 0; c < 4; ++c)
      acc[c] += sbc[c*128 + k]*wb + sccs[c*128 + k]*wc + scent[c*128 + k]*ws2;
  }
  #pragma unroll
  for (int c = 0; c < 4; ++c)
    hcent[((r*Gg + g)*4 + c)*128 + tid] = fmaxf(acc[c], 0.f);
}

// K6 (MFMA): bbsb = aggbb@Wbb + x@Wsb; per r: scb = (nm x hcent);
// h_base = relu(bbsb + scb@Wcb); mean over r; column sums -> pgsum slot.
__global__ __launch_bounds__(256)
void k_hbase(const unsigned short* __restrict__ aggbb16,
             const unsigned int* __restrict__ xh,
             const float* __restrict__ nmt, const float* __restrict__ hcent,
             const unsigned short* __restrict__ Wbbp,
             const unsigned short* __restrict__ Wsbp,
             const unsigned short* __restrict__ Wcbp,
             float* __restrict__ pgsum) {
  __shared__ unsigned short A1[64*136];
  __shared__ unsigned short A2[64*136];
  __shared__ float shc[512];
  __shared__ float snm[256];
  __shared__ float pred[128];
  int tid = threadIdx.x, n0 = blockIdx.x*64, g = n0 >> 8;
  int lane = tid & 63, wv = tid >> 6;
  int m = lane & 15, quad = lane >> 4;
  int rbase = wv*16;
  for (int j = tid; j < 1024; j += 256) {
    int row = j >> 4, col = (j & 15) * 8;
    uint4 v = *reinterpret_cast<const uint4*>(aggbb16 + (size_t)(n0+row)*128 + col);
    *reinterpret_cast<uint4*>(&A1[row*136 + col]) = v;
  }
  for (int j = tid; j < 2048; j += 256) {
    int row = j >> 5, col = (j & 31) * 4;
    uint4 v = *reinterpret_cast<const uint4*>(xh + (size_t)(n0+row)*128 + col);
    uint2 o;
    o.x = (v.x & 0xffffu) | (v.y << 16);
    o.y = (v.z & 0xffffu) | (v.w << 16);
    *reinterpret_cast<uint2*>(&A2[row*136 + col]) = o;
  }
  __syncthreads();
  f32x4 bb[8];
  #pragma unroll
  for (int nt = 0; nt < 8; ++nt) bb[nt] = (f32x4){0.f,0.f,0.f,0.f};
  const short* a1r = (const short*)&A1[(rbase + m)*136];
  const short* a2r = (const short*)&A2[(rbase + m)*136];
  #pragma unroll
  for (int nt = 0; nt < 8; ++nt) {
    #pragma unroll
    for (int kk = 0; kk < 4; ++kk) {
      int ko = kk*32 + quad*8;
      bf16x8 av1 = *reinterpret_cast<const bf16x8*>(a1r + ko);
      bf16x8 wv1 = *reinterpret_cast<const bf16x8*>((const short*)Wbbp + (nt*16 + m)*128 + ko);
      bb[nt] = __builtin_amdgcn_mfma_f32_16x16x32_bf16(av1, wv1, bb[nt], 0, 0, 0);
      bf16x8 av2 = *reinterpret_cast<const bf16x8*>(a2r + ko);
      bf16x8 wv2 = *reinterpret_cast<const bf16x8*>((const short*)Wsbp + (nt*16 + m)*128 + ko);
      bb[nt] = __builtin_amdgcn_mfma_f32_16x16x32_bf16(av2, wv2, bb[nt], 0, 0, 0);
    }
  }
  __syncthreads();
  unsigned short* SB = A2;
  f32x4 msum[8];
  #pragma unroll
  for (int nt = 0; nt < 8; ++nt) msum[nt] = (f32x4){0.f,0.f,0.f,0.f};
  for (int r = 0; r < 2; ++r) {
    for (int j = tid; j < 512; j += 256) shc[j] = hcent[((size_t)(r*Gg + g)*4)*128 + j];
    if (tid < 256) snm[tid] = nmt[(size_t)(n0 + (tid >> 2))*8 + r*4 + (tid & 3)];
    __syncthreads();
    for (int j = tid; j < 8192; j += 256) {
      int node = j >> 7, k = j & 127;
      float v = snm[node*4+0]*shc[k]       + snm[node*4+1]*shc[128 + k]
              + snm[node*4+2]*shc[256 + k] + snm[node*4+3]*shc[384 + k];
      SB[node*136 + k] = bf16bits(v);
    }
    __syncthreads();
    f32x4 aw[8];
    #pragma unroll
    for (int nt = 0; nt < 8; ++nt) aw[nt] = (f32x4){0.f,0.f,0.f,0.f};
    const short* sbr = (const short*)&SB[(rbase + m)*136];
    #pragma unroll
    for (int nt = 0; nt < 8; ++nt) {
      #pragma unroll
      for (int kk = 0; kk < 4; ++kk) {
        int ko = kk*32 + quad*8;
        bf16x8 av = *reinterpret_cast<const bf16x8*>(sbr + ko);
        bf16x8 wvv = *reinterpret_cast<const bf16x8*>((const short*)Wcbp + (nt*16 + m)*128 + ko);
        aw[nt] = __builtin_amdgcn_mfma_f32_16x16x32_bf16(av, wvv, aw[nt], 0, 0, 0);
      }
    }
    #pragma unroll
    for (int nt = 0; nt < 8; ++nt) {
      #pragma unroll
      for (int i = 0; i < 4; ++i)
        msum[nt][i] += 0.5f * fmaxf(bb[nt][i] + aw[nt][i], 0.f);
    }
    __syncthreads();
  }
  if (tid < 128) pred[tid] = 0.f;
  __syncthreads();
  #pragma unroll
  for (int nt = 0; nt < 8; ++nt) {
    float s = msum[nt][0] + msum[nt][1] + msum[nt][2] + msum[nt][3];
    atomicAdd(&pred[nt*16 + m], s);
  }
  __syncthreads();
  if (tid < 128) pgsum[(size_t)blockIdx.x*128 + tid] = pred[tid];
}

// K7: graph mean (from 4 pgsum slots) + W_inter + W_out head
__global__ __launch_bounds__(128)
void k_out(const float* __restrict__ pgsum, const float* __restrict__ Wint,
           const float* __restrict__ bint, const float* __restrict__ Wout,
           const float* __restrict__ bout, float* __restrict__ out) {
  __shared__ float ss[128], sge[128];
  int tid = threadIdx.x, g = blockIdx.x;
  float s = pgsum[(size_t)(g*4+0)*128 + tid] + pgsum[(size_t)(g*4+1)*128 + tid]
          + pgsum[(size_t)(g*4+2)*128 + tid] + pgsum[(size_t)(g*4+3)*128 + tid];
  ss[tid] = s * (1.f/256.f);
  __syncthreads();
  float ge = bint[tid];
  for (int k = 0; k < 128; ++k) ge += ss[k] * Wint[k*128 + tid];
  sge[tid] = ge;
  __syncthreads();
  if (tid < 10) {
    float o = bout[tid];
    for (int d = 0; d < 128; ++d) o += sge[d] * Wout[d*10 + tid];
    out[g*10 + tid] = o;
  }
}

extern "C" void kernel_launch(void* const* d_in, const int* in_sizes, int n_in,
                              void* d_out, int out_size, void* d_ws, size_t ws_size,
                              hipStream_t stream) {
  const float* xf   = (const float*)d_in[0];
  const float* ea   = (const float*)d_in[1];
  const float* Wa   = (const float*)d_in[2];
  const float* ba   = (const float*)d_in[3];
  const float* Wsc  = (const float*)d_in[4];
  const float* We   = (const float*)d_in[5];
  const float* Wb2c = (const float*)d_in[6];
  const float* Wbb  = (const float*)d_in[7];
  const float* Wbc  = (const float*)d_in[8];
  const float* Wcb  = (const float*)d_in[9];
  const float* WccW = (const float*)d_in[10];
  const float* Wsb  = (const float*)d_in[11];
  const float* Wsc2 = (const float*)d_in[12];
  const float* Wint = (const float*)d_in[13];
  const float* bint = (const float*)d_in[14];
  const float* Wout = (const float*)d_in[15];
  const float* bout = (const float*)d_in[16];
  const int*   ei   = (const int*)d_in[17];

  // Workspace layout (float offsets); ~95 MB
  float* ws    = (float*)d_ws;
  unsigned int* xh = (unsigned int*)ws;                      // [N,128]
  float* nmt   = ws + 4194304;                               // [N,8]
  float* hcent = ws + 4456448;                               // [R,G,4,128]
  float* wcc   = ws + 4587520;                               // [R,G,16]
  unsigned short* aggbb16 = (unsigned short*)(ws + 4591616); // [N,128] bf16
  int*   osrc  = (int*)(ws + 6688768);                       // [E] packed (dl<<16)|sl
  int*   rowst = (int*)(ws + 6950912);                       // [N]
  float* sea   = ws + 6983680;                               // [N,16]
  float* bnmp  = ws + 7507968;                               // [512][256][8]
  float* geap  = ws + 8556544;                               // [512][128]
  float* wsump = ws + 8622080;                               // [512][20]
  float* den   = ws + 12826624;                              // [8,G]
  float* pgsum = ws + 12827648;                              // [512][128]
  float* maxv  = ws + 12893184;                              // (64)
  unsigned short* Wbbp  = (unsigned short*)(ws + 12893248);  // [128][128] bf16
  unsigned short* Wsbp  = (unsigned short*)(ws + 12901440);
  unsigned short* Wcbp  = (unsigned short*)(ws + 12909632);
  unsigned short* Wap   = (unsigned short*)(ws + 12917824);  // [128][64] bf16
  unsigned short* Wb2cp = (unsigned short*)(ws + 12921920);  // [128][128] bf16
  float* bnm   = ws + 12930112;                              // [N,8]
  unsigned short* xonly = (unsigned short*)(ws + 13192256);  // [N,128] bf16
  float* pnum  = ws + 15289408;                              // [8,G,32,128]
  float* pabc  = ws + 19483712;                              // [8,G,32,128]

  k_wrep   <<<5*128,   128, 0, stream>>>(Wbb, Wsb, Wcb, Wa, Wb2c,
                                         Wbbp, Wsbp, Wcbp, Wap, Wb2cp);
  k_atom   <<<Nn/64,   256, 0, stream>>>(xf, Wap, ba, Wsc, Wb2cp, xh, xonly, nmt);
  k_gedge  <<<Gg+Gg*4, 256, 0, stream>>>(ei, nmt, ea, osrc, rowst, sea, den,
                                         bnmp, geap, wsump);
  k_wfin   <<<Gg+1,    256, 0, stream>>>(wsump, bnmp, wcc, maxv, bnm);
  k_poolagg<<<Gg*32,   256, 0, stream>>>(xh, xonly, nmt, bnm, sea, We, osrc, rowst,
                                         aggbb16, pnum, pabc);
  k_hcent  <<<2*Gg,    128, 0, stream>>>(pnum, den, pabc, geap, We, wcc, maxv,
                                         Wbc, WccW, Wsc2, hcent);
  k_hbase  <<<Nn/64,   256, 0, stream>>>(aggbb16, xh, nmt, hcent, Wbbp, Wsbp, Wcbp, pgsum);
  k_out    <<<Gg,      128, 0, stream>>>(pgsum, Wint, bint, Wout, bout, (float*)d_out);
}

// Round 17
// 257.914 us; speedup vs baseline: 1.0488x; 1.0488x over previous
//
#include <hip/hip_runtime.h>
#include <hip/hip_bf16.h>

// Problem sizes (fixed)
#define Nn 32768   // nodes
#define Ee 131072  // edges
#define Gg 128     // graphs
#define Dd 128

using bf16 = __hip_bfloat16;
typedef __attribute__((ext_vector_type(8))) short bf16x8;
typedef __attribute__((ext_vector_type(4))) float f32x4;

__device__ __forceinline__ float b2f(bf16 v){ return __bfloat162float(v); }
__device__ __forceinline__ bf16  f2b(float v){ return __float2bfloat16(v); }
__device__ __forceinline__ unsigned short bf16bits(float v){
  union { bf16 b; unsigned short u; } cv; cv.b = f2b(v); return cv.u;
}
__device__ __forceinline__ float bfu(unsigned short u){
  return __uint_as_float((unsigned int)u << 16);
}
__device__ __forceinline__ float upk_x(unsigned int v){ return __uint_as_float(v << 16); }
__device__ __forceinline__ float upk_h(unsigned int v){ return __uint_as_float(v & 0xffff0000u); }

// K0: repack weights to bf16 [n][k] (B-operand layout for MFMA)
__global__ __launch_bounds__(128)
void k_wrep(const float* __restrict__ Wbb, const float* __restrict__ Wsb,
            const float* __restrict__ Wcb, const float* __restrict__ Wa,
            const float* __restrict__ Wb2c,
            unsigned short* __restrict__ Wbbp, unsigned short* __restrict__ Wsbp,
            unsigned short* __restrict__ Wcbp, unsigned short* __restrict__ Wap,
            unsigned short* __restrict__ Wb2cp) {
  int mat = blockIdx.x >> 7, n = blockIdx.x & 127, k = threadIdx.x;
  if      (mat == 0) Wbbp [n*128 + k] = bf16bits(Wbb [k*128 + n]);
  else if (mat == 1) Wsbp [n*128 + k] = bf16bits(Wsb [k*128 + n]);
  else if (mat == 2) Wcbp [n*128 + k] = bf16bits(Wcb [k*128 + n]);
  else if (mat == 3) { if (k < 64) Wap[n*64 + k] = bf16bits(Wa[k*128 + n]); }
  else               Wb2cp[n*128 + k] = bf16bits(Wb2c[k*128 + n]);
}

// K1 (MFMA): x = xf@Wa + ba; nmt = softmax_c(x@Wsc); h = relu(x@Wb2c);
// xh = pack(x,h); xonly = bf16 x (for the narrow gather).
__global__ __launch_bounds__(256)
void k_atom(const float* __restrict__ xf, const unsigned short* __restrict__ Wap,
            const float* __restrict__ ba, const float* __restrict__ Wsc,
            const unsigned short* __restrict__ Wb2cp,
            unsigned int* __restrict__ xh, unsigned short* __restrict__ xonly,
            float* __restrict__ nmt) {
  __shared__ unsigned short sxf[64*72];
  __shared__ unsigned short sxb[64*136];
  __shared__ float ss[64*8];
  __shared__ float sWsc[1024];
  int tid = threadIdx.x, n0 = blockIdx.x*64;
  int lane = tid & 63, wv = tid >> 6;
  int m = lane & 15, quad = lane >> 4;
  int rbase = wv*16;
  #pragma unroll
  for (int k = 0; k < 4; ++k) {
    int pos = (tid + k*256)*4;
    int node = pos >> 6, f = pos & 63;
    float4 v = *reinterpret_cast<const float4*>(xf + (size_t)n0*64 + pos);
    ushort4 o;
    o.x = bf16bits(v.x); o.y = bf16bits(v.y); o.z = bf16bits(v.z); o.w = bf16bits(v.w);
    *reinterpret_cast<ushort4*>(&sxf[node*72 + f]) = o;
  }
  for (int j = tid; j < 1024; j += 256) sWsc[j] = Wsc[j];
  __syncthreads();
  f32x4 cx[8];
  #pragma unroll
  for (int nt = 0; nt < 8; ++nt) {
    float bv = ba[nt*16 + m];
    cx[nt] = (f32x4){bv, bv, bv, bv};
  }
  const unsigned short* a1 = &sxf[(rbase + m)*72];
  #pragma unroll
  for (int nt = 0; nt < 8; ++nt) {
    #pragma unroll
    for (int kk = 0; kk < 2; ++kk) {
      int ko = kk*32 + quad*8;
      bf16x8 av = *reinterpret_cast<const bf16x8*>((const short*)a1 + ko);
      bf16x8 bv8 = *reinterpret_cast<const bf16x8*>((const short*)Wap + (nt*16 + m)*64 + ko);
      cx[nt] = __builtin_amdgcn_mfma_f32_16x16x32_bf16(av, bv8, cx[nt], 0, 0, 0);
    }
  }
  #pragma unroll
  for (int nt = 0; nt < 8; ++nt)
    #pragma unroll
    for (int i = 0; i < 4; ++i)
      sxb[(rbase + quad*4 + i)*136 + nt*16 + m] = bf16bits(cx[nt][i]);
  __syncthreads();
  for (int p = tid; p < 512; p += 256) {
    int node = p >> 3, col = p & 7;
    float s = 0.f;
    for (int dd = 0; dd < 128; ++dd)
      s += bfu(sxb[node*136 + dd]) * sWsc[dd*8 + col];
    ss[node*8 + col] = s;
  }
  __syncthreads();
  if (tid < 128) {
    int node = tid >> 1, k = tid & 1;
    float v0 = ss[node*8 + 0 + k], v1 = ss[node*8 + 2 + k];
    float v2 = ss[node*8 + 4 + k], v3 = ss[node*8 + 6 + k];
    float mx = fmaxf(fmaxf(v0, v1), fmaxf(v2, v3));
    float e0 = expf(v0-mx), e1 = expf(v1-mx), e2 = expf(v2-mx), e3 = expf(v3-mx);
    float inv = 1.f / (e0+e1+e2+e3);
    *reinterpret_cast<float4*>(nmt + (size_t)(n0 + node)*8 + k*4) =
        make_float4(e0*inv, e1*inv, e2*inv, e3*inv);
  }
  f32x4 chf[8];
  #pragma unroll
  for (int nt = 0; nt < 8; ++nt) chf[nt] = (f32x4){0.f,0.f,0.f,0.f};
  const unsigned short* a2 = &sxb[(rbase + m)*136];
  #pragma unroll
  for (int nt = 0; nt < 8; ++nt) {
    #pragma unroll
    for (int kk = 0; kk < 4; ++kk) {
      int ko = kk*32 + quad*8;
      bf16x8 av = *reinterpret_cast<const bf16x8*>((const short*)a2 + ko);
      bf16x8 bv8 = *reinterpret_cast<const bf16x8*>((const short*)Wb2cp + (nt*16 + m)*128 + ko);
      chf[nt] = __builtin_amdgcn_mfma_f32_16x16x32_bf16(av, bv8, chf[nt], 0, 0, 0);
    }
  }
  #pragma unroll
  for (int nt = 0; nt < 8; ++nt) {
    #pragma unroll
    for (int i = 0; i < 4; ++i) {
      int row = rbase + quad*4 + i, col = nt*16 + m;
      float hv = fmaxf(chf[nt][i], 0.f);
      unsigned short xb = sxb[row*136 + col];
      xh[(size_t)(n0 + row)*128 + col] =
          ((unsigned int)bf16bits(hv) << 16) | (unsigned int)xb;
      xonly[(size_t)(n0 + row)*128 + col] = xb;
    }
  }
}

// K2 (merged): blocks 0..127  -> per-graph CSR build + sea + den
//              blocks 128..639 -> edge-parallel alpha/w20/beta/gea partials
// osrc entries are packed: (dst_local << 16) | src_local.
__global__ __launch_bounds__(256)
void k_gedge(const int* __restrict__ ei, const float* __restrict__ nmt,
             const float* __restrict__ ea,
             int* __restrict__ osrc, int* __restrict__ rowstart,
             float* __restrict__ sea, float* __restrict__ den,
             float* __restrict__ bnmp, float* __restrict__ geap,
             float* __restrict__ wsump) {
  __shared__ __align__(16) char smem[42576];
  int t = threadIdx.x;
  if (blockIdx.x < Gg) {
    int g = blockIdx.x;
    int* cnt    = (int*)smem;
    int* off    = cnt + 256;
    int* sdl    = off + 256;
    int* ssl    = sdl + 1024;
    int* sorder = ssl + 1024;
    float* den8 = (float*)(sorder + 1024);
    cnt[t] = 0;
    if (t < 8) den8[t] = 0.f;
    __syncthreads();
    #pragma unroll
    for (int j = 0; j < 4; ++j) {
      int e = t + j*256;
      int sl = ei[g*1024 + e] - g*256;
      int dl = ei[Ee + g*1024 + e] - g*256;
      ssl[e] = sl; sdl[e] = dl;
      atomicAdd(&cnt[dl], 1);
    }
    {
      const float4* p = reinterpret_cast<const float4*>(nmt + (size_t)(g*256 + t)*8);
      float4 a = p[0], b = p[1];
      float v[8] = {a.x,a.y,a.z,a.w,b.x,b.y,b.z,b.w};
      #pragma unroll
      for (int i = 0; i < 8; ++i) {
        float s = v[i];
        for (int o = 32; o > 0; o >>= 1) s += __shfl_xor(s, o);
        if ((t & 63) == 0) atomicAdd(&den8[i], s);
      }
    }
    __syncthreads();
    off[t] = cnt[t];
    __syncthreads();
    for (int s = 1; s < 256; s <<= 1) {
      int v = (t >= s) ? off[t - s] : 0;
      __syncthreads();
      off[t] += v;
      __syncthreads();
    }
    int startv = off[t] - cnt[t];
    int mycnt = cnt[t];
    rowstart[g*256 + t] = startv;
    off[t] = startv;
    __syncthreads();
    #pragma unroll
    for (int j = 0; j < 4; ++j) {
      int e = t + j*256;
      int pos = atomicAdd(&off[sdl[e]], 1);
      osrc[g*1024 + pos] = (sdl[e] << 16) | ssl[e];
      sorder[pos] = e;
    }
    __syncthreads();
    float s0x=0,s0y=0,s0z=0,s0w=0, s1x=0,s1y=0,s1z=0,s1w=0;
    float s2x=0,s2y=0,s2z=0,s2w=0, s3x=0,s3y=0,s3z=0,s3w=0;
    for (int jj = startv; jj < startv + mycnt; ++jj) {
      int e = sorder[jj];
      const float4* er = reinterpret_cast<const float4*>(ea + ((size_t)g*1024 + e)*16);
      float4 a0 = er[0], a1 = er[1], a2 = er[2], a3 = er[3];
      s0x+=a0.x; s0y+=a0.y; s0z+=a0.z; s0w+=a0.w;
      s1x+=a1.x; s1y+=a1.y; s1z+=a1.z; s1w+=a1.w;
      s2x+=a2.x; s2y+=a2.y; s2z+=a2.z; s2w+=a2.w;
      s3x+=a3.x; s3y+=a3.y; s3z+=a3.z; s3w+=a3.w;
    }
    float4* so = reinterpret_cast<float4*>(sea + (size_t)(g*256 + t)*16);
    so[0] = make_float4(s0x,s0y,s0z,s0w);
    so[1] = make_float4(s1x,s1y,s1z,s1w);
    so[2] = make_float4(s2x,s2y,s2z,s2w);
    so[3] = make_float4(s3x,s3y,s3z,s3w);
    if (t < 8) den[t*Gg + g] = den8[t];
  } else {
    int bq = blockIdx.x - Gg;
    float* eaT   = (float*)smem;
    float* salT  = eaT + 16*260;
    float* sbeta = salT + 8*260;
    float* red   = sbeta + 8*260;
    float* sga   = red + 20;
    float* snmt  = sga + 256;
    int g = bq >> 2;
    int ebase = g*1024 + (bq & 3)*256;
    for (int j = t; j < 2080; j += 256) sbeta[j] = 0.f;
    if (t < 20) red[t] = 0.f;
    for (int j = t; j < 2048; j += 256) snmt[j] = nmt[(size_t)g*2048 + j];
    __syncthreads();
    int sl = ei[ebase + t] - g*256;
    int dl = ei[Ee + ebase + t] - g*256;
    const float4* ps4 = reinterpret_cast<const float4*>(snmt + sl*8);
    const float4* pt4 = reinterpret_cast<const float4*>(snmt + dl*8);
    float4 sv0 = ps4[0], sv1 = ps4[1], tv0 = pt4[0], tv1 = pt4[1];
    float ps[8] = {sv0.x,sv0.y,sv0.z,sv0.w,sv1.x,sv1.y,sv1.z,sv1.w};
    float pt[8] = {tv0.x,tv0.y,tv0.z,tv0.w,tv1.x,tv1.y,tv1.z,tv1.w};
    float w20[20];
    #pragma unroll
    for (int r = 0; r < 2; ++r) {
      int b = r*4;
      w20[r*10+0] = ps[b+0]*pt[b+1]; w20[r*10+1] = ps[b+0]*pt[b+2];
      w20[r*10+2] = ps[b+0]*pt[b+3]; w20[r*10+3] = ps[b+1]*pt[b+2];
      w20[r*10+4] = ps[b+1]*pt[b+3]; w20[r*10+5] = ps[b+2]*pt[b+3];
      w20[r*10+6] = ps[b+0]*pt[b+0]; w20[r*10+7] = ps[b+1]*pt[b+1];
      w20[r*10+8] = ps[b+2]*pt[b+2]; w20[r*10+9] = ps[b+3]*pt[b+3];
    }
    #pragma unroll
    for (int rc = 0; rc < 8; ++rc) {
      float al = ps[rc]*pt[rc]*pt[rc];
      salT[rc*260 + t] = al;
      atomicAdd(&sbeta[rc*260 + sl], al);
    }
    {
      const float4* ea4 = reinterpret_cast<const float4*>(ea + (size_t)ebase*16);
      #pragma unroll
      for (int k = 0; k < 4; ++k) {
        float4 v = ea4[t*4 + k];
        eaT[(k*4+0)*260 + t] = v.x;
        eaT[(k*4+1)*260 + t] = v.y;
        eaT[(k*4+2)*260 + t] = v.z;
        eaT[(k*4+3)*260 + t] = v.w;
      }
    }
    #pragma unroll
    for (int i = 0; i < 20; ++i) {
      for (int o = 32; o > 0; o >>= 1) w20[i] += __shfl_down(w20[i], o);
    }
    if ((t & 63) == 0) {
      #pragma unroll
      for (int i = 0; i < 20; ++i) atomicAdd(&red[i], w20[i]);
    }
    __syncthreads();
    {
      int rc = t >> 5, j = (t >> 1) & 15, hf = t & 1;
      float a = 0.f;
      int eb = hf*128;
      for (int ee = eb; ee < eb + 128; ++ee)
        a += salT[rc*260 + ee] * eaT[j*260 + ee];
      sga[t] = a;
    }
    __syncthreads();
    if ((t & 1) == 0) {
      int rc = t >> 5, j = (t >> 1) & 15;
      geap[(size_t)bq*128 + rc*16 + j] = sga[t] + sga[t+1];
    }
    if (t < 20) wsump[bq*20 + t] = red[t];
    {
      float4* bo = reinterpret_cast<float4*>(bnmp + (size_t)bq*2048 + t*8);
      bo[0] = make_float4(sbeta[0*260+t], sbeta[1*260+t], sbeta[2*260+t], sbeta[3*260+t]);
      bo[1] = make_float4(sbeta[4*260+t], sbeta[5*260+t], sbeta[6*260+t], sbeta[7*260+t]);
    }
  }
}

// K3: blocks 0..127: bnm[g] = sum of 4 bnmp slots. block 128: wcc + maxv.
__global__ __launch_bounds__(256)
void k_wfin(const float* __restrict__ wsump, const float* __restrict__ bnmp,
            float* __restrict__ wcc, float* __restrict__ maxv,
            float* __restrict__ bnm) {
  int t = threadIdx.x;
  if (blockIdx.x < Gg) {
    int g = blockIdx.x;
    for (int j = t; j < 2048; j += 256) {
      float s = bnmp[(size_t)(g*4+0)*2048 + j] + bnmp[(size_t)(g*4+1)*2048 + j]
              + bnmp[(size_t)(g*4+2)*2048 + j] + bnmp[(size_t)(g*4+3)*2048 + j];
      bnm[(size_t)g*2048 + j] = s;
    }
    return;
  }
  __shared__ float smax[128];
  float mx = 0.f;
  if (t < 128) {
    float w[20];
    #pragma unroll
    for (int i = 0; i < 20; ++i)
      w[i] = wsump[(t*4+0)*20 + i] + wsump[(t*4+1)*20 + i]
           + wsump[(t*4+2)*20 + i] + wsump[(t*4+3)*20 + i];
    #pragma unroll
    for (int r = 0; r < 2; ++r) {
      #pragma unroll
      for (int ij = 0; ij < 16; ++ij) {
        int i = ij >> 2, j = ij & 3;
        float v;
        if (i == j) v = 0.5f * w[r*10 + 6 + i];
        else { int a = i < j ? i : j, b = i < j ? j : i;
               int p = (a == 0) ? (b - 1) : (a == 1) ? (b + 1) : 5;
               v = w[r*10 + p]; }
        wcc[(r*Gg + t)*16 + ij] = v;
        mx = fmaxf(mx, v);
      }
    }
    smax[t] = mx;
  }
  __syncthreads();
  for (int s = 64; s > 0; s >>= 1) {
    if (t < s) smax[t] = fmaxf(smax[t], smax[t + s]);
    __syncthreads();
  }
  if (t == 0) maxv[0] = smax[0];
}

// K4 (pool + agg): node-parallel CSR gather, Gg*32 blocks (8 nodes/block,
// 4 serial nodes/thread); in-edge loop unrolled x4 with independent
// accumulators. Narrow 2 B/lane gather from xonly.
__global__ __launch_bounds__(256)
void k_poolagg(const unsigned int* __restrict__ xh,
               const unsigned short* __restrict__ xonly,
               const float* __restrict__ nmt, const float* __restrict__ bnm,
               const float* __restrict__ sea, const float* __restrict__ We,
               const int* __restrict__ osrc, const int* __restrict__ rowstart,
               unsigned short* __restrict__ aggbb16,
               float* __restrict__ pnum, float* __restrict__ pabc) {
  __shared__ float combN[1024], combA[1024];
  int t = threadIdx.x, d = t & 127, q = t >> 7;
  int g = blockIdx.x >> 5, e32 = blockIdx.x & 31;
  int nbase = g*256 + e32*8;
  const unsigned short* xg = xonly + (size_t)g*256*128;
  const int* og = osrc + g*1024;
  float w[16];
  #pragma unroll
  for (int j = 0; j < 16; ++j) w[j] = We[j*128 + d];
  float aH[8] = {0,0,0,0,0,0,0,0};
  float aX[8] = {0,0,0,0,0,0,0,0};
  for (int nn = q; nn < 8; nn += 2) {
    int n = nbase + nn, ln = n & 255;
    unsigned int vn = xh[(size_t)n*128 + d];
    float xn = upk_x(vn), hn = upk_h(vn);
    const float4* pp = reinterpret_cast<const float4*>(nmt + (size_t)n*8);
    float4 p0 = pp[0], p1 = pp[1];
    float pc[8] = {p0.x,p0.y,p0.z,p0.w,p1.x,p1.y,p1.z,p1.w};
    const float4* bp = reinterpret_cast<const float4*>(bnm + (size_t)n*8);
    float4 b0 = bp[0], b1 = bp[1];
    float bt[8] = {b0.x,b0.y,b0.z,b0.w,b1.x,b1.y,b1.z,b1.w};
    #pragma unroll
    for (int rc = 0; rc < 8; ++rc) {
      aH[rc] += (pc[rc] + bt[rc])*hn;
      aX[rc] += pc[rc]*xn;
    }
    const float4* sp = reinterpret_cast<const float4*>(sea + (size_t)n*16);
    float4 s0 = sp[0], s1 = sp[1], s2 = sp[2], s3 = sp[3];
    float agg = s0.x*w[0] + s0.y*w[1] + s0.z*w[2] + s0.w*w[3]
              + s1.x*w[4] + s1.y*w[5] + s1.z*w[6] + s1.w*w[7]
              + s2.x*w[8] + s2.y*w[9] + s2.z*w[10]+ s2.w*w[11]
              + s3.x*w[12]+ s3.y*w[13]+ s3.z*w[14]+ s3.w*w[15];
    int start = rowstart[n];
    int end = (ln == 255) ? 1024 : rowstart[n+1];
    float a0 = 0.f, a1 = 0.f, a2 = 0.f, a3 = 0.f;
    int jj = start;
    for (; jj + 3 < end; jj += 4) {
      int q0 = og[jj+0] & 255, q1 = og[jj+1] & 255;
      int q2 = og[jj+2] & 255, q3 = og[jj+3] & 255;
      a0 += bfu(xg[(size_t)q0*128 + d]);
      a1 += bfu(xg[(size_t)q1*128 + d]);
      a2 += bfu(xg[(size_t)q2*128 + d]);
      a3 += bfu(xg[(size_t)q3*128 + d]);
    }
    for (; jj < end; ++jj)
      a0 += bfu(xg[(size_t)(og[jj] & 255)*128 + d]);
    agg += (a0 + a1) + (a2 + a3);
    aggbb16[(size_t)n*128 + d] = bf16bits(agg);
  }
  if (q == 1) {
    #pragma unroll
    for (int rc = 0; rc < 8; ++rc) { combN[rc*128+d] = aH[rc]; combA[rc*128+d] = aX[rc]; }
  }
  __syncthreads();
  if (q == 0) {
    #pragma unroll
    for (int rc = 0; rc < 8; ++rc) {
      pnum[(((size_t)rc*Gg + g)*32 + e32)*128 + d] = aH[rc] + combN[rc*128+d];
      pabc[(((size_t)rc*Gg + g)*32 + e32)*128 + d] = aX[rc] + combA[rc*128+d];
    }
  }
}

// K4b: parallel slot reduction: (rc,g) block sums 32 slots -> pnumf/pabcf
__global__ __launch_bounds__(128)
void k_pred(const float* __restrict__ pnum, const float* __restrict__ pabc,
            float* __restrict__ pnumf, float* __restrict__ pabcf) {
  int t = threadIdx.x;
  size_t b = blockIdx.x;            // rc*Gg + g
  const float* pn = pnum + b*32*128;
  const float* pa = pabc + b*32*128;
  float s0=0,s1=0,s2=0,s3=0, a0=0,a1=0,a2=0,a3=0;
  #pragma unroll
  for (int s = 0; s < 32; s += 4) {
    s0 += pn[(s+0)*128+t]; s1 += pn[(s+1)*128+t];
    s2 += pn[(s+2)*128+t]; s3 += pn[(s+3)*128+t];
    a0 += pa[(s+0)*128+t]; a1 += pa[(s+1)*128+t];
    a2 += pa[(s+2)*128+t]; a3 += pa[(s+3)*128+t];
  }
  pnumf[b*128+t] = (s0+s1)+(s2+s3);
  pabcf[b*128+t] = (a0+a1)+(a2+a3);
}

// K5: cent_x = (pnumf + gea@We)/(den+1e-6);
//     h_cent = relu(abc@Wbc + (Wcc_n@cent)@Wcc + cent@Wsc)
__global__ __launch_bounds__(128)
void k_hcent(const float* __restrict__ pnumf, const float* __restrict__ den,
             const float* __restrict__ pabcf, const float* __restrict__ geap,
             const float* __restrict__ We, const float* __restrict__ wcc,
             const float* __restrict__ maxv,
             const float* __restrict__ Wbc, const float* __restrict__ Wcc_,
             const float* __restrict__ Wsc2, float* __restrict__ hcent) {
  __shared__ float scent[512], sbc[512], sccs[512], swcc[16], sgea[64];
  int tid = threadIdx.x, r = blockIdx.x >> 7, g = blockIdx.x & 127;
  float inv = 1.f / (maxv[0] + 1e-9f);
  if (tid < 16) swcc[tid] = wcc[(r*Gg + g)*16 + tid] * inv;
  if (tid < 64) {
    int c = tid >> 4, j = tid & 15;
    int idx = (r*4 + c)*16 + j;
    sgea[tid] = geap[(size_t)(g*4+0)*128 + idx] + geap[(size_t)(g*4+1)*128 + idx]
              + geap[(size_t)(g*4+2)*128 + idx] + geap[(size_t)(g*4+3)*128 + idx];
  }
  __syncthreads();
  for (int c = 0; c < 4; ++c) {
    int rc = r*4 + c;
    float nv = pnumf[((size_t)rc*Gg + g)*128 + tid];
    float av = pabcf[((size_t)rc*Gg + g)*128 + tid];
    #pragma unroll
    for (int j = 0; j < 16; ++j) nv += sgea[c*16 + j] * We[j*128 + tid];
    float dn = den[rc*Gg + g] + 1e-6f;
    scent[c*128 + tid] = nv / dn;
    sbc[c*128 + tid]   = av;
  }
  __syncthreads();
  for (int i = 0; i < 4; ++i) {
    sccs[i*128 + tid] = swcc[i*4+0]*scent[tid]       + swcc[i*4+1]*scent[128 + tid]
                      + swcc[i*4+2]*scent[256 + tid] + swcc[i*4+3]*scent[384 + tid];
  }
  __syncthreads();
  float acc[4] = {0.f, 0.f, 0.f, 0.f};
  for (int k = 0; k < 128; ++k) {
    float wb = Wbc[k*128 + tid], wc = Wcc_[k*128 + tid], ws2 = Wsc2[k*128 + tid];
    #pragma unroll
    for (int c = 0; c < 4; ++c)
      acc[c] += sbc[c*128 + k]*wb + sccs[c*128 + k]*wc + scent[c*128 + k]*ws2;
  }
  #pragma unroll
  for (int c = 0; c < 4; ++c)
    hcent[((r*Gg + g)*4 + c)*128 + tid] = fmaxf(acc[c], 0.f);
}

// K6 (MFMA): bbsb = aggbb@Wbb + x@Wsb; per r: scb = (nm x hcent);
// h_base = relu(bbsb + scb@Wcb); mean over r; column sums -> pgsum slot.
__global__ __launch_bounds__(256)
void k_hbase(const unsigned short* __restrict__ aggbb16,
             const unsigned int* __restrict__ xh,
             const float* __restrict__ nmt, const float* __restrict__ hcent,
             const unsigned short* __restrict__ Wbbp,
             const unsigned short* __restrict__ Wsbp,
             const unsigned short* __restrict__ Wcbp,
             float* __restrict__ pgsum) {
  __shared__ unsigned short A1[64*136];
  __shared__ unsigned short A2[64*136];
  __shared__ float shc[512];
  __shared__ float snm[256];
  __shared__ float pred[128];
  int tid = threadIdx.x, n0 = blockIdx.x*64, g = n0 >> 8;
  int lane = tid & 63, wv = tid >> 6;
  int m = lane & 15, quad = lane >> 4;
  int rbase = wv*16;
  for (int j = tid; j < 1024; j += 256) {
    int row = j >> 4, col = (j & 15) * 8;
    uint4 v = *reinterpret_cast<const uint4*>(aggbb16 + (size_t)(n0+row)*128 + col);
    *reinterpret_cast<uint4*>(&A1[row*136 + col]) = v;
  }
  for (int j = tid; j < 2048; j += 256) {
    int row = j >> 5, col = (j & 31) * 4;
    uint4 v = *reinterpret_cast<const uint4*>(xh + (size_t)(n0+row)*128 + col);
    uint2 o;
    o.x = (v.x & 0xffffu) | (v.y << 16);
    o.y = (v.z & 0xffffu) | (v.w << 16);
    *reinterpret_cast<uint2*>(&A2[row*136 + col]) = o;
  }
  __syncthreads();
  f32x4 bb[8];
  #pragma unroll
  for (int nt = 0; nt < 8; ++nt) bb[nt] = (f32x4){0.f,0.f,0.f,0.f};
  const short* a1r = (const short*)&A1[(rbase + m)*136];
  const short* a2r = (const short*)&A2[(rbase + m)*136];
  #pragma unroll
  for (int nt = 0; nt < 8; ++nt) {
    #pragma unroll
    for (int kk = 0; kk < 4; ++kk) {
      int ko = kk*32 + quad*8;
      bf16x8 av1 = *reinterpret_cast<const bf16x8*>(a1r + ko);
      bf16x8 wv1 = *reinterpret_cast<const bf16x8*>((const short*)Wbbp + (nt*16 + m)*128 + ko);
      bb[nt] = __builtin_amdgcn_mfma_f32_16x16x32_bf16(av1, wv1, bb[nt], 0, 0, 0);
      bf16x8 av2 = *reinterpret_cast<const bf16x8*>(a2r + ko);
      bf16x8 wv2 = *reinterpret_cast<const bf16x8*>((const short*)Wsbp + (nt*16 + m)*128 + ko);
      bb[nt] = __builtin_amdgcn_mfma_f32_16x16x32_bf16(av2, wv2, bb[nt], 0, 0, 0);
    }
  }
  __syncthreads();
  unsigned short* SB = A2;
  f32x4 msum[8];
  #pragma unroll
  for (int nt = 0; nt < 8; ++nt) msum[nt] = (f32x4){0.f,0.f,0.f,0.f};
  for (int r = 0; r < 2; ++r) {
    for (int j = tid; j < 512; j += 256) shc[j] = hcent[((size_t)(r*Gg + g)*4)*128 + j];
    if (tid < 256) snm[tid] = nmt[(size_t)(n0 + (tid >> 2))*8 + r*4 + (tid & 3)];
    __syncthreads();
    for (int j = tid; j < 8192; j += 256) {
      int node = j >> 7, k = j & 127;
      float v = snm[node*4+0]*shc[k]       + snm[node*4+1]*shc[128 + k]
              + snm[node*4+2]*shc[256 + k] + snm[node*4+3]*shc[384 + k];
      SB[node*136 + k] = bf16bits(v);
    }
    __syncthreads();
    f32x4 aw[8];
    #pragma unroll
    for (int nt = 0; nt < 8; ++nt) aw[nt] = (f32x4){0.f,0.f,0.f,0.f};
    const short* sbr = (const short*)&SB[(rbase + m)*136];
    #pragma unroll
    for (int nt = 0; nt < 8; ++nt) {
      #pragma unroll
      for (int kk = 0; kk < 4; ++kk) {
        int ko = kk*32 + quad*8;
        bf16x8 av = *reinterpret_cast<const bf16x8*>(sbr + ko);
        bf16x8 wvv = *reinterpret_cast<const bf16x8*>((const short*)Wcbp + (nt*16 + m)*128 + ko);
        aw[nt] = __builtin_amdgcn_mfma_f32_16x16x32_bf16(av, wvv, aw[nt], 0, 0, 0);
      }
    }
    #pragma unroll
    for (int nt = 0; nt < 8; ++nt) {
      #pragma unroll
      for (int i = 0; i < 4; ++i)
        msum[nt][i] += 0.5f * fmaxf(bb[nt][i] + aw[nt][i], 0.f);
    }
    __syncthreads();
  }
  if (tid < 128) pred[tid] = 0.f;
  __syncthreads();
  #pragma unroll
  for (int nt = 0; nt < 8; ++nt) {
    float s = msum[nt][0] + msum[nt][1] + msum[nt][2] + msum[nt][3];
    atomicAdd(&pred[nt*16 + m], s);
  }
  __syncthreads();
  if (tid < 128) pgsum[(size_t)blockIdx.x*128 + tid] = pred[tid];
}

// K7: graph mean (from 4 pgsum slots) + W_inter + W_out head
__global__ __launch_bounds__(128)
void k_out(const float* __restrict__ pgsum, const float* __restrict__ Wint,
           const float* __restrict__ bint, const float* __restrict__ Wout,
           const float* __restrict__ bout, float* __restrict__ out) {
  __shared__ float ss[128], sge[128];
  int tid = threadIdx.x, g = blockIdx.x;
  float s = pgsum[(size_t)(g*4+0)*128 + tid] + pgsum[(size_t)(g*4+1)*128 + tid]
          + pgsum[(size_t)(g*4+2)*128 + tid] + pgsum[(size_t)(g*4+3)*128 + tid];
  ss[tid] = s * (1.f/256.f);
  __syncthreads();
  float ge = bint[tid];
  for (int k = 0; k < 128; ++k) ge += ss[k] * Wint[k*128 + tid];
  sge[tid] = ge;
  __syncthreads();
  if (tid < 10) {
    float o = bout[tid];
    for (int d = 0; d < 128; ++d) o += sge[d] * Wout[d*10 + tid];
    out[g*10 + tid] = o;
  }
}

extern "C" void kernel_launch(void* const* d_in, const int* in_sizes, int n_in,
                              void* d_out, int out_size, void* d_ws, size_t ws_size,
                              hipStream_t stream) {
  const float* xf   = (const float*)d_in[0];
  const float* ea   = (const float*)d_in[1];
  const float* Wa   = (const float*)d_in[2];
  const float* ba   = (const float*)d_in[3];
  const float* Wsc  = (const float*)d_in[4];
  const float* We   = (const float*)d_in[5];
  const float* Wb2c = (const float*)d_in[6];
  const float* Wbb  = (const float*)d_in[7];
  const float* Wbc  = (const float*)d_in[8];
  const float* Wcb  = (const float*)d_in[9];
  const float* WccW = (const float*)d_in[10];
  const float* Wsb  = (const float*)d_in[11];
  const float* Wsc2 = (const float*)d_in[12];
  const float* Wint = (const float*)d_in[13];
  const float* bint = (const float*)d_in[14];
  const float* Wout = (const float*)d_in[15];
  const float* bout = (const float*)d_in[16];
  const int*   ei   = (const int*)d_in[17];

  // Workspace layout (float offsets); ~96 MB
  float* ws    = (float*)d_ws;
  unsigned int* xh = (unsigned int*)ws;                      // [N,128]
  float* nmt   = ws + 4194304;                               // [N,8]
  float* hcent = ws + 4456448;                               // [R,G,4,128]
  float* wcc   = ws + 4587520;                               // [R,G,16]
  unsigned short* aggbb16 = (unsigned short*)(ws + 4591616); // [N,128] bf16
  int*   osrc  = (int*)(ws + 6688768);                       // [E] packed (dl<<16)|sl
  int*   rowst = (int*)(ws + 6950912);                       // [N]
  float* sea   = ws + 6983680;                               // [N,16]
  float* bnmp  = ws + 7507968;                               // [512][256][8]
  float* geap  = ws + 8556544;                               // [512][128]
  float* wsump = ws + 8622080;                               // [512][20]
  float* den   = ws + 12826624;                              // [8,G]
  float* pgsum = ws + 12827648;                              // [512][128]
  float* maxv  = ws + 12893184;                              // (64)
  unsigned short* Wbbp  = (unsigned short*)(ws + 12893248);  // [128][128] bf16
  unsigned short* Wsbp  = (unsigned short*)(ws + 12901440);
  unsigned short* Wcbp  = (unsigned short*)(ws + 12909632);
  unsigned short* Wap   = (unsigned short*)(ws + 12917824);  // [128][64] bf16
  unsigned short* Wb2cp = (unsigned short*)(ws + 12921920);  // [128][128] bf16
  float* bnm   = ws + 12930112;                              // [N,8]
  unsigned short* xonly = (unsigned short*)(ws + 13192256);  // [N,128] bf16
  float* pnum  = ws + 15289408;                              // [8,G,32,128]
  float* pabc  = ws + 19483712;                              // [8,G,32,128]
  float* pnumf = ws + 23678016;                              // [8,G,128]
  float* pabcf = ws + 23809088;                              // [8,G,128]

  k_wrep   <<<5*128,   128, 0, stream>>>(Wbb, Wsb, Wcb, Wa, Wb2c,
                                         Wbbp, Wsbp, Wcbp, Wap, Wb2cp);
  k_atom   <<<Nn/64,   256, 0, stream>>>(xf, Wap, ba, Wsc, Wb2cp, xh, xonly, nmt);
  k_gedge  <<<Gg+Gg*4, 256, 0, stream>>>(ei, nmt, ea, osrc, rowst, sea, den,
                                         bnmp, geap, wsump);
  k_wfin   <<<Gg+1,    256, 0, stream>>>(wsump, bnmp, wcc, maxv, bnm);
  k_poolagg<<<Gg*32,   256, 0, stream>>>(xh, xonly, nmt, bnm, sea, We, osrc, rowst,
                                         aggbb16, pnum, pabc);
  k_pred   <<<8*Gg,    128, 0, stream>>>(pnum, pabc, pnumf, pabcf);
  k_hcent  <<<2*Gg,    128, 0, stream>>>(pnumf, den, pabcf, geap, We, wcc, maxv,
                                         Wbc, WccW, Wsc2, hcent);
  k_hbase  <<<Nn/64,   256, 0, stream>>>(aggbb16, xh, nmt, hcent, Wbbp, Wsbp, Wcbp, pgsum);
  k_out    <<<Gg,      128, 0, stream>>>(pgsum, Wint, bint, Wout, bout, (float*)d_out);
}